// Round 26
// baseline (30.418 us; speedup 1.0000x reference)
//
#include <hip/hip_runtime.h>

// RNNFFT: depth-10 radix-2 butterfly network over last dim (1024).
// v = x; for l = 9..0: y = B_l(w_l * v); v = (l==1) ? y : x + y
// Pairs at level l: (e, e^h), h = 512>>l. Twiddle: bw[OFF[l] + (e & (n_l-1))].
// Mix (lw^T): role-j: y = lw[j][j]*t_self + lw[1-j][j]*t_partner.
//
// Structure = r24 (best, 29.5us): 256-thr blocks, two-layout butterfly,
// shared per-wave xr/v A->B buffer, nt stores. LDS 24KB -> 6 blocks/CU.
// This round: B-TWIDDLE TRANSPOSED LDS COPY. r24 read B-twiddles as 30
// scattered b32 (lane l needs bw[off+j*64+l], j=0..nr-1 - scattered in
// A-order storage). Staging now builds a TRANSPOSED copy in the same
// 2048-float footprint: B0[l*16+j]=bw[j*64+l] (L0, [0,1024)),
// B1[l*8+j]=bw[1024+j*64+l] ([1024,1536)), B2[l*4+j] ([1536,1792)),
// B3[l*2+j] ([1792,1920)); A-section [1920,2016) unchanged (loadw_A as-is).
// B-twiddle reads: 30 b32 -> 8 vector reads (4+2+1+1 b128/b64). Staging
// 2 -> ~8 write instrs/thread (scattered b32). Net -16 DS instrs/wave at
// zero register/LDS/occupancy cost. Same swz() bank spread on all accesses.
// Per-element arithmetic identical to r11 (absmax 7.450581e-9).

constexpr int VECLEN = 1024;

__device__ __forceinline__ int swz(int f) {      // XOR bits[4:2] with bits[7:5]
  return f ^ (((f >> 5) & 7) << 2);              // preserves 16B (4-float) groups
}

template<int L, bool RESL>
__device__ __forceinline__ void level_inlane(float (&v)[16], const float (&xr)[16],
                                             const float* __restrict__ bw,
                                             const float* __restrict__ lw) {
  constexpr int n = VECLEN >> L;          // 16, 8, 4, 2
  constexpr int h = n >> 1;               // 8, 4, 2, 1
  constexpr int off = 2048 - (2048 >> L); // OFFSETS[L]
  float w[n];                              // lane-uniform -> scalar loads
#pragma unroll
  for (int i = 0; i < n; ++i) w[i] = bw[off + i];
  const float l00 = lw[L*4+0], l01 = lw[L*4+1], l10 = lw[L*4+2], l11 = lw[L*4+3];
#pragma unroll
  for (int r = 0; r < 16; ++r) {
    if ((r & h) == 0) {
      const int q = r ^ h;
      const float t0 = w[r & (n-1)] * v[r];
      const float t1 = w[q & (n-1)] * v[q];
      const float y0 = l00*t0 + l10*t1;   // role 0 (exact r11 ordering)
      const float y1 = l01*t0 + l11*t1;   // role 1
      v[r] = RESL ? xr[r] + y0 : y0;
      v[q] = RESL ? xr[q] + y1 : y1;
    }
  }
}

template<int L, bool RESL>
__device__ __forceinline__ void level_dpp(float (&v)[16], const float (&xr)[16],
                                          const float (&w)[16],
                                          const float* __restrict__ lw, int lane) {
  static_assert(L == 4 || L == 5, "DPP levels only");
  constexpr int ctl = (L == 5) ? 0xB1 : 0x4E;
  const int role = (lane >> (5 - L)) & 1;
  const float l00 = lw[L*4+0], l01 = lw[L*4+1], l10 = lw[L*4+2], l11 = lw[L*4+3];
  const float cs = role ? l11 : l00;      // coeff on own t
  const float cp = role ? l01 : l10;      // coeff on partner t
#pragma unroll
  for (int r = 0; r < 16; ++r) {
    const float t = w[r] * v[r];
    const float tp = __int_as_float(
        __builtin_amdgcn_update_dpp(0, __float_as_int(t), ctl, 0xF, 0xF, true));
    const float y = cs*t + cp*tp;
    v[r] = RESL ? xr[r] + y : y;
  }
}

template<int L>
__device__ __forceinline__ void loadw_A(float (&w)[16], const float* lds_bw, int lane) {
  constexpr int n = VECLEN >> L;          // L5: 32, L4: 64
  constexpr int off = 2048 - (2048 >> L); // 1984, 1920  (A-section kept as-is)
  const int f0 = off + ((lane * 16) & (n - 1));
#pragma unroll
  for (int k = 0; k < 4; ++k) {
    const float4 f = *reinterpret_cast<const float4*>(lds_bw + swz(f0 + 4*k));
    w[4*k+0]=f.x; w[4*k+1]=f.y; w[4*k+2]=f.z; w[4*k+3]=f.w;
  }
}

// Transposed B-twiddle reads: per-lane CONTIGUOUS after rearranged staging.
__device__ __forceinline__ void loadw_B0(float (&w)[16], const float* lds_bw, int lane) {
  const int b = lane * 16;                 // region [0,1024)
#pragma unroll
  for (int k = 0; k < 4; ++k) {
    const float4 f = *reinterpret_cast<const float4*>(lds_bw + swz(b + 4*k));
    w[4*k+0]=f.x; w[4*k+1]=f.y; w[4*k+2]=f.z; w[4*k+3]=f.w;
  }
}
__device__ __forceinline__ void loadw_B1(float (&w)[8], const float* lds_bw, int lane) {
  const int b = 1024 + lane * 8;           // region [1024,1536)
#pragma unroll
  for (int k = 0; k < 2; ++k) {
    const float4 f = *reinterpret_cast<const float4*>(lds_bw + swz(b + 4*k));
    w[4*k+0]=f.x; w[4*k+1]=f.y; w[4*k+2]=f.z; w[4*k+3]=f.w;
  }
}
__device__ __forceinline__ void loadw_B2(float (&w)[4], const float* lds_bw, int lane) {
  const float4 f = *reinterpret_cast<const float4*>(lds_bw + swz(1536 + lane * 4));
  w[0]=f.x; w[1]=f.y; w[2]=f.z; w[3]=f.w;  // region [1536,1792)
}
__device__ __forceinline__ void loadw_B3(float (&w)[2], const float* lds_bw, int lane) {
  const int b = 1792 + lane * 2;           // region [1792,1920); same 16B group
  const float2 f = *reinterpret_cast<const float2*>(lds_bw + swz(b));
  w[0]=f.x; w[1]=f.y;
}

template<int L, bool RESL>
__device__ __forceinline__ void level_B(float (&v)[16], const float (&xr)[16],
                                        const float* w, const float* __restrict__ lw) {
  constexpr int nr = (VECLEN >> L) >> 6;   // 16, 8, 4, 2
  constexpr int hb = nr >> 1;              // 8, 4, 2, 1
  const float l00 = lw[L*4+0], l01 = lw[L*4+1], l10 = lw[L*4+2], l11 = lw[L*4+3];
#pragma unroll
  for (int r = 0; r < 16; ++r) {
    if ((r & hb) == 0) {
      const int q = r ^ hb;
      const float t0 = w[r & (nr-1)] * v[r];
      const float t1 = w[q & (nr-1)] * v[q];
      const float y0 = l00*t0 + l10*t1;
      const float y1 = l01*t0 + l11*t1;
      v[r] = RESL ? xr[r] + y0 : y0;
      v[q] = RESL ? xr[q] + y1 : y1;
    }
  }
}

__global__ __launch_bounds__(256)
void rnnfft_kernel(const float* __restrict__ x,
                   const float* __restrict__ bw,
                   const float* __restrict__ lw,
                   float* __restrict__ out, int nvec) {
  __shared__ float lds_bw[2048];           // rearranged bw (8 KB)
  __shared__ float tbuf[4][1024];          // per-wave SHARED xr/v buffer (16 KB)
  const int t = threadIdx.x;
  const int w4 = t >> 6;
  const int lane = t & 63;
  const int wid = blockIdx.x * 4 + w4;     // wave id = vector id (grid exact)
  const size_t base = (size_t)wid * VECLEN;
  float* buf = tbuf[w4];

  // x in layout A (the ONLY global read of x).
  float v[16], xr[16];
#pragma unroll
  for (int k = 0; k < 4; ++k) {
    const float4 f = *reinterpret_cast<const float4*>(x + base + lane*16 + 4*k);
    xr[4*k+0]=f.x; xr[4*k+1]=f.y; xr[4*k+2]=f.z; xr[4*k+3]=f.w;
  }

  // Stash xr into the shared per-wave buffer (first use of the buffer).
#pragma unroll
  for (int k = 0; k < 4; ++k) {
    float4 f;
    f.x = xr[4*k+0]; f.y = xr[4*k+1]; f.z = xr[4*k+2]; f.w = xr[4*k+3];
    *reinterpret_cast<float4*>(buf + swz(lane*16 + 4*k)) = f;
  }

  // Stage bw into LDS, once per block. B-sections [0,1920) are TRANSPOSED
  // per level (lane-contiguous for loadw_B*); A-section [1920,2016) as-is.
  if (t < 240) {                           // 8 floats each, scattered b32
    const float4 a = *reinterpret_cast<const float4*>(bw + 8*t);
    const float4 b = *reinterpret_cast<const float4*>(bw + 8*t + 4);
    const float s[8] = {a.x,a.y,a.z,a.w,b.x,b.y,b.z,b.w};
#pragma unroll
    for (int k = 0; k < 8; ++k) {
      const int i = 8*t + k;
      int dest;
      if (i < 1024)      { dest = ((i & 63) * 16) + (i >> 6); }                  // L0
      else if (i < 1536) { const int m = i - 1024; dest = 1024 + (m & 63)*8 + (m >> 6); } // L1
      else if (i < 1792) { const int m = i - 1536; dest = 1536 + (m & 63)*4 + (m >> 6); } // L2
      else               { const int m = i - 1792; dest = 1792 + (m & 63)*2 + (m >> 6); } // L3
      lds_bw[swz(dest)] = s[k];
    }
  } else if (t < 252) {                    // A-section [1920,2016): b128 pair
    const float4 a = *reinterpret_cast<const float4*>(bw + 8*t);
    const float4 b = *reinterpret_cast<const float4*>(bw + 8*t + 4);
    *reinterpret_cast<float4*>(lds_bw + swz(8*t)) = a;
    *reinterpret_cast<float4*>(lds_bw + swz(8*t+4)) = b;
  }
  __syncthreads();

#pragma unroll
  for (int r = 0; r < 16; ++r) v[r] = xr[r];

  // Prefetch DPP-level twiddles from LDS (land during in-lane levels).
  float wA[16], wB[16];
  loadw_A<5>(wA, lds_bw, lane);
  loadw_A<4>(wB, lds_bw, lane);

  // Layout A: levels 9..6 in-lane, 5 and 4 via DPP.
  level_inlane<9, true>(v, xr, bw, lw);
  level_inlane<8, true>(v, xr, bw, lw);
  level_inlane<7, true>(v, xr, bw, lw);
  level_inlane<6, true>(v, xr, bw, lw);
  level_dpp<5, true>(v, xr, wA, lw, lane);
  level_dpp<4, true>(v, xr, wB, lw, lane);

  // Read xr back in B layout BEFORE overwriting the buffer with v.
  float xrB[16];
#pragma unroll
  for (int r = 0; r < 16; ++r) xrB[r] = buf[swz(r*64 + lane)];

  // Transpose v: A -> B through the same buffer.
#pragma unroll
  for (int k = 0; k < 4; ++k) {
    float4 f;
    f.x = v[4*k+0]; f.y = v[4*k+1]; f.z = v[4*k+2]; f.w = v[4*k+3];
    *reinterpret_cast<float4*>(buf + swz(lane*16 + 4*k)) = f;
  }

  // B-twiddles: vectorized reads from the transposed copy (8 instrs total).
  float w3[2], w2[4], w1[8], w0[16];
  loadw_B3(w3, lds_bw, lane);
  loadw_B2(w2, lds_bw, lane);

#pragma unroll
  for (int r = 0; r < 16; ++r) v[r] = buf[swz(r*64 + lane)];

  // Layout B: levels 3..0 all in-lane (pure VALU).
  level_B<3, true >(v, xrB, w3, lw);
  loadw_B1(w1, lds_bw, lane);
  level_B<2, true >(v, xrB, w2, lw);
  loadw_B0(w0, lds_bw, lane);
  level_B<1, false>(v, xrB, w1, lw);   // RES[1] = False
  level_B<0, true >(v, xrB, w0, lw);

  // Nontemporal coalesced stores (r22 win: out stops polluting caches).
#pragma unroll
  for (int r = 0; r < 16; ++r)
    __builtin_nontemporal_store(v[r], &out[base + r*64 + lane]);
}

extern "C" void kernel_launch(void* const* d_in, const int* in_sizes, int n_in,
                              void* d_out, int out_size, void* d_ws, size_t ws_size,
                              hipStream_t stream) {
  const float* x  = (const float*)d_in[0];
  const float* bw = (const float*)d_in[1];
  const float* lw = (const float*)d_in[2];
  float* out = (float*)d_out;
  const int nvec = in_sizes[0] / VECLEN;        // 16384 vectors
  const int wpb = 4;                            // waves per block (256 threads)
  const int blocks = (nvec + wpb - 1) / wpb;    // 4096, exact
  rnnfft_kernel<<<blocks, 256, 0, stream>>>(x, bw, lw, out, nvec);
}

// Round 27
// 30.395 us; speedup vs baseline: 1.0008x; 1.0008x over previous
//
#include <hip/hip_runtime.h>

// RNNFFT: depth-10 radix-2 butterfly network over last dim (1024).
// v = x; for l = 9..0: y = B_l(w_l * v); v = (l==1) ? y : x + y
// Pairs at level l: (e, e^h), h = 512>>l. Twiddle: bw[OFF[l] + (e & (n_l-1))].
// Mix (lw^T): role-j: y = lw[j][j]*t_self + lw[1-j][j]*t_partner.
//
// Structure = r24 (best, 29.5us) + SEQUENTIAL PAIR PER WAVE:
//   Layout A (e=lane*16+r): levels 9..6 in-lane; 5,4 via DPP quad_perm.
//   bw staged in LDS (r24 layout — r26's transposed staging hit 852K bank
//   conflicts, reverted). Shared per-wave 4KB xr/v A->B buffer. nt stores.
//   Layout B (e=r*64+lane): levels 3..0 in-lane.
// Mechanism: r24's per-wave dead time is the EXPOSED ENDS (start x-load with
// nothing to cover it; end store drain). Each wave now does vectors 2w,2w+1:
// b's x-load issues mid-B(a) (covered), a's stores drain under A(b) (covered),
// staging+barrier amortized 2x, 8192 waves. Peak live ~75-85 regs is FREE:
// LDS caps 6 blocks/CU = 6 waves/SIMD, so VGPR<=84 costs no occupancy
// (r24 used only 40; r3/r12/r18 spilled because occupancy incentive existed).
// Per-element arithmetic identical to r11/r24 (absmax 7.450581e-9).

constexpr int VECLEN = 1024;

__device__ __forceinline__ int swz(int f) {      // XOR bits[4:2] with bits[7:5]
  return f ^ (((f >> 5) & 7) << 2);              // preserves 16B groups
}

template<int L, bool RESL>
__device__ __forceinline__ void level_inlane(float (&v)[16], const float (&xr)[16],
                                             const float* __restrict__ bw,
                                             const float* __restrict__ lw) {
  constexpr int n = VECLEN >> L;          // 16, 8, 4, 2
  constexpr int h = n >> 1;               // 8, 4, 2, 1
  constexpr int off = 2048 - (2048 >> L); // OFFSETS[L]
  float w[n];                              // lane-uniform -> scalar loads
#pragma unroll
  for (int i = 0; i < n; ++i) w[i] = bw[off + i];
  const float l00 = lw[L*4+0], l01 = lw[L*4+1], l10 = lw[L*4+2], l11 = lw[L*4+3];
#pragma unroll
  for (int r = 0; r < 16; ++r) {
    if ((r & h) == 0) {
      const int q = r ^ h;
      const float t0 = w[r & (n-1)] * v[r];
      const float t1 = w[q & (n-1)] * v[q];
      const float y0 = l00*t0 + l10*t1;   // role 0 (exact r11 ordering)
      const float y1 = l01*t0 + l11*t1;   // role 1
      v[r] = RESL ? xr[r] + y0 : y0;
      v[q] = RESL ? xr[q] + y1 : y1;
    }
  }
}

template<int L, bool RESL>
__device__ __forceinline__ void level_dpp(float (&v)[16], const float (&xr)[16],
                                          const float (&w)[16],
                                          const float* __restrict__ lw, int lane) {
  static_assert(L == 4 || L == 5, "DPP levels only");
  constexpr int ctl = (L == 5) ? 0xB1 : 0x4E;
  const int role = (lane >> (5 - L)) & 1;
  const float l00 = lw[L*4+0], l01 = lw[L*4+1], l10 = lw[L*4+2], l11 = lw[L*4+3];
  const float cs = role ? l11 : l00;      // coeff on own t
  const float cp = role ? l01 : l10;      // coeff on partner t
#pragma unroll
  for (int r = 0; r < 16; ++r) {
    const float t = w[r] * v[r];
    const float tp = __int_as_float(
        __builtin_amdgcn_update_dpp(0, __float_as_int(t), ctl, 0xF, 0xF, true));
    const float y = cs*t + cp*tp;
    v[r] = RESL ? xr[r] + y : y;
  }
}

template<int L>
__device__ __forceinline__ void loadw_A(float (&w)[16], const float* lds_bw, int lane) {
  constexpr int n = VECLEN >> L;
  constexpr int off = 2048 - (2048 >> L);
  const int f0 = off + ((lane * 16) & (n - 1));
#pragma unroll
  for (int k = 0; k < 4; ++k) {
    const float4 f = *reinterpret_cast<const float4*>(lds_bw + swz(f0 + 4*k));
    w[4*k+0]=f.x; w[4*k+1]=f.y; w[4*k+2]=f.z; w[4*k+3]=f.w;
  }
}

template<int L>
__device__ __forceinline__ void loadw_B(float* w, const float* lds_bw, int lane) {
  constexpr int off = 2048 - (2048 >> L);
  constexpr int nr = (VECLEN >> L) >> 6;   // 16, 8, 4, 2
#pragma unroll
  for (int j = 0; j < nr; ++j)
    w[j] = lds_bw[swz(off + j*64 + lane)];
}

template<int L, bool RESL>
__device__ __forceinline__ void level_B(float (&v)[16], const float (&xr)[16],
                                        const float* w, const float* __restrict__ lw) {
  constexpr int nr = (VECLEN >> L) >> 6;   // 16, 8, 4, 2
  constexpr int hb = nr >> 1;              // 8, 4, 2, 1
  const float l00 = lw[L*4+0], l01 = lw[L*4+1], l10 = lw[L*4+2], l11 = lw[L*4+3];
#pragma unroll
  for (int r = 0; r < 16; ++r) {
    if ((r & hb) == 0) {
      const int q = r ^ hb;
      const float t0 = w[r & (nr-1)] * v[r];
      const float t1 = w[q & (nr-1)] * v[q];
      const float y0 = l00*t0 + l10*t1;
      const float y1 = l01*t0 + l11*t1;
      v[r] = RESL ? xr[r] + y0 : y0;
      v[q] = RESL ? xr[q] + y1 : y1;
    }
  }
}

__device__ __forceinline__ void loadX_A(float (&xr)[16], const float* __restrict__ x,
                                        size_t base, int lane) {
#pragma unroll
  for (int k = 0; k < 4; ++k) {
    const float4 f = *reinterpret_cast<const float4*>(x + base + lane*16 + 4*k);
    xr[4*k+0]=f.x; xr[4*k+1]=f.y; xr[4*k+2]=f.z; xr[4*k+3]=f.w;
  }
}

// Phase A (levels 9..4) + transpose-write of v into buf.
__device__ __forceinline__ void phaseA_and_writeV(float (&v)[16], const float (&xr)[16],
                                                  float* buf, const float* lds_bw,
                                                  const float* __restrict__ bw,
                                                  const float* __restrict__ lw, int lane) {
  float wA[16], wB[16];
  loadw_A<5>(wA, lds_bw, lane);
  loadw_A<4>(wB, lds_bw, lane);
  level_inlane<9, true>(v, xr, bw, lw);
  level_inlane<8, true>(v, xr, bw, lw);
  level_inlane<7, true>(v, xr, bw, lw);
  level_inlane<6, true>(v, xr, bw, lw);
  level_dpp<5, true>(v, xr, wA, lw, lane);
  level_dpp<4, true>(v, xr, wB, lw, lane);
}

// Phase B (levels 3..0) on v with residual xrB, then nt store.
__device__ __forceinline__ void phaseB_and_store(float (&v)[16], const float (&xrB)[16],
                                                 const float* lds_bw,
                                                 const float* __restrict__ lw,
                                                 float* __restrict__ out,
                                                 size_t base, int lane) {
  float w3[2], w2[4], w1[8], w0[16];
  loadw_B<3>(w3, lds_bw, lane);
  loadw_B<2>(w2, lds_bw, lane);
  level_B<3, true >(v, xrB, w3, lw);
  loadw_B<1>(w1, lds_bw, lane);
  level_B<2, true >(v, xrB, w2, lw);
  loadw_B<0>(w0, lds_bw, lane);
  level_B<1, false>(v, xrB, w1, lw);   // RES[1] = False
  level_B<0, true >(v, xrB, w0, lw);
#pragma unroll
  for (int r = 0; r < 16; ++r)
    __builtin_nontemporal_store(v[r], &out[base + r*64 + lane]);
}

__global__ __launch_bounds__(256)
void rnnfft_kernel(const float* __restrict__ x,
                   const float* __restrict__ bw,
                   const float* __restrict__ lw,
                   float* __restrict__ out, int nvec) {
  __shared__ float lds_bw[2048];           // swizzled bw[0..2016)  (8 KB)
  __shared__ float tbuf[4][1024];          // per-wave SHARED xr/v buffer (16 KB)
  const int t = threadIdx.x;
  const int w4 = t >> 6;
  const int lane = t & 63;
  const int wid = blockIdx.x * 4 + w4;     // wave id; vectors 2*wid, 2*wid+1
  const size_t baseA = (size_t)(2 * wid) * VECLEN;
  const size_t baseB = baseA + VECLEN;
  float* buf = tbuf[w4];

  // ---- vector a: load + stash residual in buf ----
  float v[16], xr[16];
  loadX_A(xr, x, baseA, lane);
#pragma unroll
  for (int k = 0; k < 4; ++k) {
    float4 f;
    f.x = xr[4*k+0]; f.y = xr[4*k+1]; f.z = xr[4*k+2]; f.w = xr[4*k+3];
    *reinterpret_cast<float4*>(buf + swz(lane*16 + 4*k)) = f;
  }

  // Stage bw[0..2016) into LDS (swizzled, r24 layout), once per block.
  if (t < 252) {
    const float4 a = *reinterpret_cast<const float4*>(bw + 8*t);
    const float4 b = *reinterpret_cast<const float4*>(bw + 8*t + 4);
    *reinterpret_cast<float4*>(lds_bw + swz(8*t)) = a;
    *reinterpret_cast<float4*>(lds_bw + swz(8*t+4)) = b;
  }
  __syncthreads();

#pragma unroll
  for (int r = 0; r < 16; ++r) v[r] = xr[r];
  phaseA_and_writeV(v, xr, buf, lds_bw, bw, lw, lane);

  // Read a's residual back in B layout BEFORE overwriting buf with v(a).
  float xrB[16];
#pragma unroll
  for (int r = 0; r < 16; ++r) xrB[r] = buf[swz(r*64 + lane)];
#pragma unroll
  for (int k = 0; k < 4; ++k) {
    float4 f;
    f.x = v[4*k+0]; f.y = v[4*k+1]; f.z = v[4*k+2]; f.w = v[4*k+3];
    *reinterpret_cast<float4*>(buf + swz(lane*16 + 4*k)) = f;
  }

  // Issue vector b's x-load NOW — its latency is covered by phase B(a).
  float xn[16];
  loadX_A(xn, x, baseB, lane);

#pragma unroll
  for (int r = 0; r < 16; ++r) v[r] = buf[swz(r*64 + lane)];
  phaseB_and_store(v, xrB, lds_bw, lw, out, baseA, lane);

  // ---- vector b: buf is free (vB(a) reads executed before these writes) ----
#pragma unroll
  for (int k = 0; k < 4; ++k) {
    float4 f;
    f.x = xn[4*k+0]; f.y = xn[4*k+1]; f.z = xn[4*k+2]; f.w = xn[4*k+3];
    *reinterpret_cast<float4*>(buf + swz(lane*16 + 4*k)) = f;
  }
#pragma unroll
  for (int r = 0; r < 16; ++r) v[r] = xn[r];
  // a's nt stores drain underneath phase A(b).
  phaseA_and_writeV(v, xn, buf, lds_bw, bw, lw, lane);

#pragma unroll
  for (int r = 0; r < 16; ++r) xrB[r] = buf[swz(r*64 + lane)];
#pragma unroll
  for (int k = 0; k < 4; ++k) {
    float4 f;
    f.x = v[4*k+0]; f.y = v[4*k+1]; f.z = v[4*k+2]; f.w = v[4*k+3];
    *reinterpret_cast<float4*>(buf + swz(lane*16 + 4*k)) = f;
  }
#pragma unroll
  for (int r = 0; r < 16; ++r) v[r] = buf[swz(r*64 + lane)];
  phaseB_and_store(v, xrB, lds_bw, lw, out, baseB, lane);
}

extern "C" void kernel_launch(void* const* d_in, const int* in_sizes, int n_in,
                              void* d_out, int out_size, void* d_ws, size_t ws_size,
                              hipStream_t stream) {
  const float* x  = (const float*)d_in[0];
  const float* bw = (const float*)d_in[1];
  const float* lw = (const float*)d_in[2];
  float* out = (float*)d_out;
  const int nvec = in_sizes[0] / VECLEN;        // 16384 vectors
  const int nwave = nvec / 2;                   // 8192 waves (2 vectors each)
  const int wpb = 4;                            // waves per block (256 threads)
  const int blocks = (nwave + wpb - 1) / wpb;   // 2048, exact
  rnnfft_kernel<<<blocks, 256, 0, stream>>>(x, bw, lw, out, nvec);
}

// Round 28
// 28.520 us; speedup vs baseline: 1.0666x; 1.0657x over previous
//
#include <hip/hip_runtime.h>

// RNNFFT: depth-10 radix-2 butterfly network over last dim (1024).
// v = x; for l = 9..0: y = B_l(w_l * v); v = (l==1) ? y : x + y
// Pairs at level l: (e, e^h), h = 512>>l. Twiddle: bw[OFF[l] + (e & (n_l-1))].
// Mix (lw^T): role-j: y = lw[j][j]*t_self + lw[1-j][j]*t_partner.
//
// Structure = r24 (best, 29.5us): 256-thr blocks, two-layout butterfly,
// shared per-wave 4KB xr/v A->B buffer, bw staged in LDS, nt stores.
// LDS 24KB -> 6 blocks/CU. VALUBusy 43% = half the wave slot is VALU issue.
// This round: FMA-FUSED RESIDUAL. v = xr + (c0*t0 + c1*t1) becomes
// v = fma(c0,t0, fma(c1,t1, xr)) - per butterfly pair 8 -> 6 VALU ops
// (-25% of level math, ~160 ops/wave). LEDGER CORRECTION: r7's absmax 0.094
// was blamed on this fusion, but r8 reverted it with absmax BIT-IDENTICAL
// and r9 showed the real bug was the permlane32_swap select. The fusion was
// never numerically tested alone; expected re-association error ~1e-6..1e-4
// vs threshold 0.109. All else identical to r24.

constexpr int VECLEN = 1024;

__device__ __forceinline__ int swz(int f) {      // XOR bits[4:2] with bits[7:5]
  return f ^ (((f >> 5) & 7) << 2);              // preserves 16B groups
}

template<int L, bool RESL>
__device__ __forceinline__ void level_inlane(float (&v)[16], const float (&xr)[16],
                                             const float* __restrict__ bw,
                                             const float* __restrict__ lw) {
  constexpr int n = VECLEN >> L;          // 16, 8, 4, 2
  constexpr int h = n >> 1;               // 8, 4, 2, 1
  constexpr int off = 2048 - (2048 >> L); // OFFSETS[L]
  float w[n];                              // lane-uniform -> scalar loads
#pragma unroll
  for (int i = 0; i < n; ++i) w[i] = bw[off + i];
  const float l00 = lw[L*4+0], l01 = lw[L*4+1], l10 = lw[L*4+2], l11 = lw[L*4+3];
#pragma unroll
  for (int r = 0; r < 16; ++r) {
    if ((r & h) == 0) {
      const int q = r ^ h;
      const float t0 = w[r & (n-1)] * v[r];
      const float t1 = w[q & (n-1)] * v[q];
      if (RESL) {
        v[r] = __builtin_fmaf(l00, t0, __builtin_fmaf(l10, t1, xr[r]));  // role 0
        v[q] = __builtin_fmaf(l11, t1, __builtin_fmaf(l01, t0, xr[q]));  // role 1
      } else {
        v[r] = l00*t0 + l10*t1;
        v[q] = l01*t0 + l11*t1;
      }
    }
  }
}

template<int L, bool RESL>
__device__ __forceinline__ void level_dpp(float (&v)[16], const float (&xr)[16],
                                          const float (&w)[16],
                                          const float* __restrict__ lw, int lane) {
  static_assert(L == 4 || L == 5, "DPP levels only");
  constexpr int ctl = (L == 5) ? 0xB1 : 0x4E;
  const int role = (lane >> (5 - L)) & 1;
  const float l00 = lw[L*4+0], l01 = lw[L*4+1], l10 = lw[L*4+2], l11 = lw[L*4+3];
  const float cs = role ? l11 : l00;      // coeff on own t
  const float cp = role ? l01 : l10;      // coeff on partner t
#pragma unroll
  for (int r = 0; r < 16; ++r) {
    const float t = w[r] * v[r];
    const float tp = __int_as_float(
        __builtin_amdgcn_update_dpp(0, __float_as_int(t), ctl, 0xF, 0xF, true));
    if (RESL) v[r] = __builtin_fmaf(cs, t, __builtin_fmaf(cp, tp, xr[r]));
    else      v[r] = cs*t + cp*tp;
  }
}

template<int L>
__device__ __forceinline__ void loadw_A(float (&w)[16], const float* lds_bw, int lane) {
  constexpr int n = VECLEN >> L;
  constexpr int off = 2048 - (2048 >> L);
  const int f0 = off + ((lane * 16) & (n - 1));
#pragma unroll
  for (int k = 0; k < 4; ++k) {
    const float4 f = *reinterpret_cast<const float4*>(lds_bw + swz(f0 + 4*k));
    w[4*k+0]=f.x; w[4*k+1]=f.y; w[4*k+2]=f.z; w[4*k+3]=f.w;
  }
}

template<int L>
__device__ __forceinline__ void loadw_B(float* w, const float* lds_bw, int lane) {
  constexpr int off = 2048 - (2048 >> L);
  constexpr int nr = (VECLEN >> L) >> 6;   // 16, 8, 4, 2
#pragma unroll
  for (int j = 0; j < nr; ++j)
    w[j] = lds_bw[swz(off + j*64 + lane)];
}

template<int L, bool RESL>
__device__ __forceinline__ void level_B(float (&v)[16], const float (&xr)[16],
                                        const float* w, const float* __restrict__ lw) {
  constexpr int nr = (VECLEN >> L) >> 6;   // 16, 8, 4, 2
  constexpr int hb = nr >> 1;              // 8, 4, 2, 1
  const float l00 = lw[L*4+0], l01 = lw[L*4+1], l10 = lw[L*4+2], l11 = lw[L*4+3];
#pragma unroll
  for (int r = 0; r < 16; ++r) {
    if ((r & hb) == 0) {
      const int q = r ^ hb;
      const float t0 = w[r & (nr-1)] * v[r];
      const float t1 = w[q & (nr-1)] * v[q];
      if (RESL) {
        v[r] = __builtin_fmaf(l00, t0, __builtin_fmaf(l10, t1, xr[r]));
        v[q] = __builtin_fmaf(l11, t1, __builtin_fmaf(l01, t0, xr[q]));
      } else {
        v[r] = l00*t0 + l10*t1;
        v[q] = l01*t0 + l11*t1;
      }
    }
  }
}

__global__ __launch_bounds__(256)
void rnnfft_kernel(const float* __restrict__ x,
                   const float* __restrict__ bw,
                   const float* __restrict__ lw,
                   float* __restrict__ out, int nvec) {
  __shared__ float lds_bw[2048];           // swizzled bw[0..2016)  (8 KB)
  __shared__ float tbuf[4][1024];          // per-wave SHARED xr/v buffer (16 KB)
  const int t = threadIdx.x;
  const int w4 = t >> 6;
  const int lane = t & 63;
  const int wid = blockIdx.x * 4 + w4;     // wave id = vector id (grid exact)
  const size_t base = (size_t)wid * VECLEN;
  float* buf = tbuf[w4];

  // x in layout A (the ONLY global read of x).
  float v[16], xr[16];
#pragma unroll
  for (int k = 0; k < 4; ++k) {
    const float4 f = *reinterpret_cast<const float4*>(x + base + lane*16 + 4*k);
    xr[4*k+0]=f.x; xr[4*k+1]=f.y; xr[4*k+2]=f.z; xr[4*k+3]=f.w;
  }

  // Stash xr into the shared per-wave buffer (first use of the buffer).
#pragma unroll
  for (int k = 0; k < 4; ++k) {
    float4 f;
    f.x = xr[4*k+0]; f.y = xr[4*k+1]; f.z = xr[4*k+2]; f.w = xr[4*k+3];
    *reinterpret_cast<float4*>(buf + swz(lane*16 + 4*k)) = f;
  }

  // Stage bw[0..2016) into LDS (swizzled), once per block.
  if (t < 252) {
    const float4 a = *reinterpret_cast<const float4*>(bw + 8*t);
    const float4 b = *reinterpret_cast<const float4*>(bw + 8*t + 4);
    *reinterpret_cast<float4*>(lds_bw + swz(8*t)) = a;
    *reinterpret_cast<float4*>(lds_bw + swz(8*t+4)) = b;
  }
  __syncthreads();

#pragma unroll
  for (int r = 0; r < 16; ++r) v[r] = xr[r];

  // Prefetch DPP-level twiddles from LDS (land during in-lane levels).
  float wA[16], wB[16];
  loadw_A<5>(wA, lds_bw, lane);
  loadw_A<4>(wB, lds_bw, lane);

  // Layout A: levels 9..6 in-lane, 5 and 4 via DPP.
  level_inlane<9, true>(v, xr, bw, lw);
  level_inlane<8, true>(v, xr, bw, lw);
  level_inlane<7, true>(v, xr, bw, lw);
  level_inlane<6, true>(v, xr, bw, lw);
  level_dpp<5, true>(v, xr, wA, lw, lane);
  level_dpp<4, true>(v, xr, wB, lw, lane);

  // Read xr back in B layout BEFORE overwriting the buffer with v.
  float xrB[16];
#pragma unroll
  for (int r = 0; r < 16; ++r) xrB[r] = buf[swz(r*64 + lane)];

  // Transpose v: A -> B through the same buffer.
#pragma unroll
  for (int k = 0; k < 4; ++k) {
    float4 f;
    f.x = v[4*k+0]; f.y = v[4*k+1]; f.z = v[4*k+2]; f.w = v[4*k+3];
    *reinterpret_cast<float4*>(buf + swz(lane*16 + 4*k)) = f;
  }

  // B-twiddles for the first two B-levels ride the same DS queue.
  float w3[2], w2[4], w1[8], w0[16];
  loadw_B<3>(w3, lds_bw, lane);
  loadw_B<2>(w2, lds_bw, lane);

#pragma unroll
  for (int r = 0; r < 16; ++r) v[r] = buf[swz(r*64 + lane)];

  // Layout B: levels 3..0 all in-lane (pure VALU).
  level_B<3, true >(v, xrB, w3, lw);
  loadw_B<1>(w1, lds_bw, lane);
  level_B<2, true >(v, xrB, w2, lw);
  loadw_B<0>(w0, lds_bw, lane);
  level_B<1, false>(v, xrB, w1, lw);   // RES[1] = False
  level_B<0, true >(v, xrB, w0, lw);

  // Nontemporal coalesced stores (r22 win: out stops polluting caches).
#pragma unroll
  for (int r = 0; r < 16; ++r)
    __builtin_nontemporal_store(v[r], &out[base + r*64 + lane]);
}

extern "C" void kernel_launch(void* const* d_in, const int* in_sizes, int n_in,
                              void* d_out, int out_size, void* d_ws, size_t ws_size,
                              hipStream_t stream) {
  const float* x  = (const float*)d_in[0];
  const float* bw = (const float*)d_in[1];
  const float* lw = (const float*)d_in[2];
  float* out = (float*)d_out;
  const int nvec = in_sizes[0] / VECLEN;        // 16384 vectors
  const int wpb = 4;                            // waves per block (256 threads)
  const int blocks = (nvec + wpb - 1) / wpb;    // 4096, exact
  rnnfft_kernel<<<blocks, 256, 0, stream>>>(x, bw, lw, out, nvec);
}